// Round 1
// baseline (34028.320 us; speedup 1.0000x reference)
//
#include <hip/hip_runtime.h>
#include <math.h>

// Problem constants
#define B 128
#define T 1024
#define E 256
#define H 512

// ws layout (floats):
//   h_buf : 2 * [512][128]  (double-buffered, [unit][batch])
//   last_h: [512][128]
//   last_c: [512][128]
//   ctrs  : 8 group barrier counters, 64-int stride (cacheline separated)
#define HBUF_OFF   0
#define LASTH_OFF  (2*65536)
#define LASTC_OFF  (3*65536)
#define CTR_OFF    (4*65536)

// Accurate transcendentals (OCML expf/tanhf): matched np bit-exact previously.
__device__ __forceinline__ float sigm_f(float x) {
    return 1.f / (1.f + expf(-x));
}
__device__ __forceinline__ float tanh_f(float x) {
    return tanhf(x);
}
__device__ __forceinline__ void fma4(float4& a, const float4 w, const float4 x) {
    a.x = fmaf(w.x, x.x, a.x);
    a.y = fmaf(w.y, x.y, a.y);
    a.z = fmaf(w.z, x.z, a.z);
    a.w = fmaf(w.w, x.w, a.w);
}

// ---------------------------------------------------------------------------
// Persistent LSTM: the whole T=1024 step loop in one kernel.
// 256 blocks x 1024 threads, 1 block/CU (cooperative launch => co-residency).
// Decomposition identical to the proven per-step kernel:
//   g = bid>>5 (8 batch groups of 16), m = bid&31 (32 unit groups of 16).
// Cross-block dependency is ONLY h(t) within a batch group (32 blocks):
//   - h exchanged via agent-scope relaxed atomics (LLC-coherent, no L2 inv,
//     weights stay L2-resident across all steps).
//   - per-group generation barrier: release fetch_add + relaxed spin.
//     __syncthreads() before arrival drains vmcnt => h stores visible.
//   - 2 h buffers + 1 barrier/step is race-free: readers of h(t) finish
//     before arriving at barrier t; writers of h(t+2) start after barrier t+1.
// c tile is block-owned => lives in LDS for the whole kernel.
__global__ __launch_bounds__(1024) void lstm_persistent(
    const int* __restrict__ tokens, const float* __restrict__ emb,
    const float* __restrict__ W_ih, const float* __restrict__ b_ih,
    const float* __restrict__ W_hh, const float* __restrict__ b_hh,
    const float* __restrict__ h0, const float* __restrict__ c0,
    float* __restrict__ ws) {
    const int tid = threadIdx.x, bid = blockIdx.x;
    const int g = bid >> 5, m = bid & 31;

    float* h_buf  = ws + HBUF_OFF;
    float* last_h = ws + LASTH_OFF;
    float* last_c = ws + LASTC_OFF;
    int*   my_ctr = (int*)(ws + CTR_OFF) + g * 64;

    __shared__ __align__(16) float  xh[16 * 772];   // [b][k], row-padded 768->772
    __shared__ float4 part[4 * 256];                // [kq][ul*16+b]
    __shared__ int    s_L[16];                      // per-batch Lsteps
    __shared__ float  s_c[256];                     // c[ul*16+b], block-owned

    // ---- per-batch lengths (all 32 blocks of a group compute identical s_L/Tg)
    if (tid < 16) s_L[tid] = T;
    __syncthreads();
    {
        const int b = tid >> 6;
        const int* tb = tokens + (size_t)(g * 16 + b) * T;
        int fz = T;
        for (int p = (tid & 63); p < T; p += 64)
            if (tb[p] == 0) fz = min(fz, p);
        atomicMin(&s_L[b], fz);
    }
    __syncthreads();
    if (tid < 16) {
        const int f = s_L[tid];
        s_L[tid] = (f == 0 || f == T) ? T : f;
    }
    __syncthreads();
    int Tg = 0;
#pragma unroll
    for (int i = 0; i < 16; ++i) Tg = max(Tg, s_L[i]);

    // ---- init block-owned c tile (same thread reads it later; no sync needed)
    if (tid < 256) {
        const int uli = tid >> 4, bi = tid & 15;
        s_c[tid] = c0[(size_t)(g * 16 + bi) * H + (m * 16 + uli)];
    }

    // ---- compute-role constants
    const int kq = tid >> 8, ul = (tid >> 4) & 15, cb = tid & 15;
    const int unit = m * 16 + ul;
    const float4* Wi = (const float4*)W_ih;
    const float4* Wh = (const float4*)W_hh;
    const float4* wr0 = Wi + (size_t)(unit) * 64;
    const float4* wr1 = Wi + (size_t)(H + unit) * 64;
    const float4* wr2 = Wi + (size_t)(2 * H + unit) * 64;
    const float4* wr3 = Wi + (size_t)(3 * H + unit) * 64;
    const float4* vr0 = Wh + (size_t)(unit) * 128;
    const float4* vr1 = Wh + (size_t)(H + unit) * 128;
    const float4* vr2 = Wh + (size_t)(2 * H + unit) * 128;
    const float4* vr3 = Wh + (size_t)(3 * H + unit) * 128;
    const int k4lo = kq * 48, k4hi = k4lo + 48;
    const int xlo = min(k4lo, 64), xhi = min(k4hi, 64);
    const int hlo = max(k4lo, 64) - 64, hhi = max(k4hi, 64) - 64;
    const float4* xb = (const float4*)&xh[cb * 772];

    // ---- epilogue constants (valid/used for tid<256; reads are in-bounds for all)
    const int ul2 = tid >> 4, b2 = tid & 15;
    const int unit2 = m * 16 + (ul2 & 15);
    const int bg = g * 16 + b2;
    // hoisted bias LOADS (addition order in-loop kept identical to old kernel)
    const float bi_i = b_ih[unit2],         bh_i = b_hh[unit2];
    const float bi_f = b_ih[H + unit2],     bh_f = b_hh[H + unit2];
    const float bi_g = b_ih[2 * H + unit2], bh_g = b_hh[2 * H + unit2];
    const float bi_o = b_ih[3 * H + unit2], bh_o = b_hh[3 * H + unit2];

    for (int t = 0; t < Tg; ++t) {
        // ---- stage x = emb[token]: 16 rows x 64 float4, 1 per thread
        {
            const int b = tid >> 6, kq4 = tid & 63;
            const int tok = tokens[(size_t)(g * 16 + b) * T + t];
            ((float4*)&xh[b * 772])[kq4] =
                ((const float4*)emb)[(size_t)tok * 64 + kq4];
        }
        // ---- stage h(t): xh[b][256+u]
        if (t == 0) {
            // directly from h0 (b-major), float4 over u
            const int b = tid >> 6, l = tid & 63;
            const float4* h04 = (const float4*)(h0 + (size_t)(g * 16 + b) * H);
            float4* dst = (float4*)&xh[b * 772 + 256];
            dst[l]      = h04[l];
            dst[64 + l] = h04[64 + l];
        } else {
            // device-coherent dword loads (bypass L1/L2 -> see sibling blocks'
            // stores at the LLC; no cache invalidate => weights stay in L2)
            float* hsrc = h_buf + (size_t)(t & 1) * (H * B);
            float hv[8];
#pragma unroll
            for (int j = 0; j < 8; ++j) {
                const int idx = j * 1024 + tid;
                const int u = idx >> 4, b = idx & 15;
                hv[j] = __hip_atomic_load(&hsrc[u * B + g * 16 + b],
                                          __ATOMIC_RELAXED,
                                          __HIP_MEMORY_SCOPE_AGENT);
            }
#pragma unroll
            for (int j = 0; j < 8; ++j) {
                const int idx = j * 1024 + tid;
                const int u = idx >> 4, b = idx & 15;
                xh[b * 772 + 256 + u] = hv[j];
            }
        }
        __syncthreads();

        // ---- K-split partial dots (identical arithmetic to old step_kernel)
        float4 s0 = {0, 0, 0, 0}, s1 = {0, 0, 0, 0};
        float4 s2 = {0, 0, 0, 0}, s3 = {0, 0, 0, 0};
#pragma unroll 4
        for (int k4 = xlo; k4 < xhi; ++k4) {
            const float4 x = xb[k4];
            fma4(s0, wr0[k4], x);
            fma4(s1, wr1[k4], x);
            fma4(s2, wr2[k4], x);
            fma4(s3, wr3[k4], x);
        }
#pragma unroll 4
        for (int k4 = hlo; k4 < hhi; ++k4) {
            const float4 x = xb[64 + k4];
            fma4(s0, vr0[k4], x);
            fma4(s1, vr1[k4], x);
            fma4(s2, vr2[k4], x);
            fma4(s3, vr3[k4], x);
        }
        float4 p;
        p.x = s0.x + s0.y + s0.z + s0.w;
        p.y = s1.x + s1.y + s1.z + s1.w;
        p.z = s2.x + s2.y + s2.z + s2.w;
        p.w = s3.x + s3.y + s3.z + s3.w;
        part[kq * 256 + (ul * 16 + cb)] = p;
        __syncthreads();

        // ---- finish gates + elementwise (tid<256)
        if (tid < 256) {
            const float4 q0 = part[tid],       q1 = part[256 + tid];
            const float4 q2 = part[512 + tid], q3 = part[768 + tid];
            const float ai = (q0.x + q1.x) + (q2.x + q3.x) + bi_i + bh_i;
            const float af = (q0.y + q1.y) + (q2.y + q3.y) + bi_f + bh_f;
            const float ag = (q0.z + q1.z) + (q2.z + q3.z) + bi_g + bh_g;
            const float ao = (q0.w + q1.w) + (q2.w + q3.w) + bi_o + bh_o;

            const float ig = sigm_f(ai);
            const float fg = sigm_f(af);
            const float gv = tanh_f(ag);
            const float og = sigm_f(ao);

            const float c_old = s_c[tid];
            const float c_new = fg * c_old + ig * gv;
            const float h_new = og * tanh_f(c_new);
            s_c[tid] = c_new;

            const int idx = unit2 * B + bg;
            __hip_atomic_store(&h_buf[(size_t)((t + 1) & 1) * (H * B) + idx],
                               h_new, __ATOMIC_RELAXED,
                               __HIP_MEMORY_SCOPE_AGENT);
            if (t == s_L[b2] - 1) {
                last_h[idx] = h_new;
                last_c[idx] = c_new;
            }
        }

        // ---- per-group barrier (skip after the last step: h(Tg) never read)
        if (t < Tg - 1) {
            __syncthreads();  // drains vmcnt: all block h-stores at coherence pt
            if (tid == 0) {
                __hip_atomic_fetch_add(my_ctr, 1, __ATOMIC_RELEASE,
                                       __HIP_MEMORY_SCOPE_AGENT);
                const int target = 32 * (t + 1);
                while (__hip_atomic_load(my_ctr, __ATOMIC_RELAXED,
                                         __HIP_MEMORY_SCOPE_AGENT) < target) {
                }
            }
            __syncthreads();
        }
    }
}

// ---------------------------------------------------------------------------
// final: y = [h;c] @ W_proj^T + b_proj ; out = y @ W_out^T + b_out
// grid 128 x 256 (unchanged)
__global__ __launch_bounds__(256) void final_kernel(
    const float* __restrict__ ws_ro, const float* __restrict__ W_proj,
    const float* __restrict__ b_proj, const float* __restrict__ W_out,
    const float* __restrict__ b_out, float* __restrict__ out) {
    const int bg = blockIdx.x, tid = threadIdx.x;
    const float* last_h = ws_ro + LASTH_OFF;
    const float* last_c = ws_ro + LASTC_OFF;

    __shared__ __align__(16) float s_hc[2 * H];
    __shared__ float s_y[H];
    for (int u = tid; u < H; u += 256) {
        s_hc[u]     = last_h[u * B + bg];
        s_hc[H + u] = last_c[u * B + bg];
    }
    __syncthreads();

    const float4* hc4 = (const float4*)s_hc;
    const float4* Wp4 = (const float4*)W_proj;
#pragma unroll
    for (int jj = 0; jj < 2; ++jj) {
        const int j = tid + jj * 256;
        const float4* wr = Wp4 + (size_t)j * 256;
        float4 acc = {0, 0, 0, 0};
#pragma unroll 4
        for (int kq = 0; kq < 256; ++kq) fma4(acc, wr[kq], hc4[kq]);
        s_y[j] = acc.x + acc.y + acc.z + acc.w + b_proj[j];
    }
    __syncthreads();

    if (tid < 64) {
        float p0 = 0.f, p1 = 0.f;
        for (int j = tid; j < H; j += 64) {
            const float y = s_y[j];
            p0 = fmaf(y, W_out[j], p0);
            p1 = fmaf(y, W_out[H + j], p1);
        }
#pragma unroll
        for (int off = 32; off; off >>= 1) {
            p0 += __shfl_down(p0, off);
            p1 += __shfl_down(p1, off);
        }
        if (tid == 0) {
            out[bg * 2 + 0] = p0 + b_out[0];
            out[bg * 2 + 1] = p1 + b_out[1];
        }
    }
}

// ---------------------------------------------------------------------------
extern "C" void kernel_launch(void* const* d_in, const int* in_sizes, int n_in,
                              void* d_out, int out_size, void* d_ws, size_t ws_size,
                              hipStream_t stream) {
    const int*   tokens = (const int*)d_in[0];
    const float* emb    = (const float*)d_in[1];
    const float* W_ih   = (const float*)d_in[2];
    const float* b_ih   = (const float*)d_in[3];
    const float* W_hh   = (const float*)d_in[4];
    const float* b_hh   = (const float*)d_in[5];
    const float* W_proj = (const float*)d_in[6];
    const float* b_proj = (const float*)d_in[7];
    const float* W_out  = (const float*)d_in[8];
    const float* b_out  = (const float*)d_in[9];
    const float* h0     = (const float*)d_in[10];
    const float* c0     = (const float*)d_in[11];
    float* out = (float*)d_out;
    float* ws  = (float*)d_ws;

    // zero the 8 barrier counters (required every launch/replay)
    hipMemsetAsync((char*)d_ws + (size_t)CTR_OFF * sizeof(float), 0,
                   8 * 64 * sizeof(int), stream);

    void* kargs[] = {(void*)&tokens, (void*)&emb, (void*)&W_ih, (void*)&b_ih,
                     (void*)&W_hh, (void*)&b_hh, (void*)&h0, (void*)&c0,
                     (void*)&ws};
    // cooperative launch: guarantees all 256 blocks co-resident (1/CU),
    // which the per-group spin barrier requires.
    hipLaunchCooperativeKernel((const void*)lstm_persistent, dim3(256),
                               dim3(1024), kargs, 0, stream);

    hipLaunchKernelGGL(final_kernel, dim3(B), dim3(256), 0, stream,
                       ws, W_proj, b_proj, W_out, b_out, out);
}